// Round 10
// baseline (32.972 us; speedup 1.0000x reference)
//
#include <hip/hip_runtime.h>
#include <hip/hip_bf16.h>

#define N_ROWS 2048
#define D_IN   256
#define D_OUT  64
#define ALPHA  0.2f
#define LN_EPS 1e-5f

typedef __attribute__((ext_vector_type(4))) float f32x4;
typedef __attribute__((ext_vector_type(8))) short s16x8;

static __device__ __forceinline__ unsigned short f2bf(float x) {
    unsigned u = __float_as_uint(x);
    unsigned r = (u + 0x7FFFu + ((u >> 16) & 1u)) >> 16;   // RTN-even
    return (unsigned short)r;
}
static __device__ __forceinline__ float bf2f(unsigned short u) {
    return __uint_as_float(((unsigned)u) << 16);
}

// ---------------------------------------------------------------------------
// K1: h = LN(F @ phiW^T + phiB); s = h . muW; H^T bf16 hi/lo planes.
// 256 blocks x 256 threads, 8 rows/block (2 rows/wave). Single 64KB phiW
// stage, column-rotation swizzle (conflict-free b128). R7-verified.
// ---------------------------------------------------------------------------
__global__ __launch_bounds__(256) void k1_h_s(
    const float* __restrict__ F, const float* __restrict__ phiW,
    const float* __restrict__ phiB, const float* __restrict__ lnG,
    const float* __restrict__ lnB, const float* __restrict__ muW,
    float* __restrict__ s_buf, unsigned short* __restrict__ HhiT,
    unsigned short* __restrict__ HloT)
{
    __shared__ f32x4 phiS[64 * 64];          // 64 KB, column-rotated
    __shared__ unsigned short Thi[64][8];
    __shared__ unsigned short Tlo[64][8];

    const int tid  = threadIdx.x;
    const int w    = tid >> 6;
    const int lane = tid & 63;
    const int i_base = blockIdx.x * 8;
    const int r0 = i_base + w * 2;             // 2 rows per wave

    const f32x4* phiW4 = (const f32x4*)phiW;   // [64][64] f32x4
    const f32x4* F4    = (const f32x4*)F;      // [2048][64] f32x4

    #pragma unroll
    for (int t = 0; t < 16; ++t) {             // stage 64KB, rotated cols
        int idx = tid + t * 256;
        int d = idx >> 6, g = idx & 63;
        phiS[(d << 6) | ((g + d) & 63)] = phiW4[idx];
    }
    __syncthreads();

    float acc[2] = {0.f, 0.f};
    #pragma unroll 8
    for (int g = 0; g < 64; ++g) {
        f32x4 p = phiS[(lane << 6) | ((g + lane) & 63)];
        #pragma unroll
        for (int rr = 0; rr < 2; ++rr) {
            f32x4 f = F4[(r0 + rr) * 64 + g];  // wave-uniform address
            acc[rr] += p.x * f.x + p.y * f.y + p.z * f.z + p.w * f.w;
        }
    }

    const float pb = phiB[lane], gg = lnG[lane], bb = lnB[lane], mw = muW[lane];

    #pragma unroll
    for (int rr = 0; rr < 2; ++rr) {
        float h = acc[rr] + pb;
        float m = h;
        #pragma unroll
        for (int off = 32; off >= 1; off >>= 1) m += __shfl_xor(m, off);
        m *= (1.f / 64.f);
        float c = h - m;
        float v = c * c;
        #pragma unroll
        for (int off = 32; off >= 1; off >>= 1) v += __shfl_xor(v, off);
        v *= (1.f / 64.f);
        float hn = c * rsqrtf(v + LN_EPS) * gg + bb;
        float sp = hn * mw;
        #pragma unroll
        for (int off = 32; off >= 1; off >>= 1) sp += __shfl_xor(sp, off);
        if (lane == 0) s_buf[r0 + rr] = sp;
        unsigned short hi = f2bf(hn);
        unsigned short lo = f2bf(hn - bf2f(hi));
        Thi[lane][w * 2 + rr] = hi;
        Tlo[lane][w * 2 + rr] = lo;
    }
    __syncthreads();
    if (tid < 128) {   // transposed store: H^T[d][i_base .. i_base+7]
        int d = tid >> 1, half = tid & 1;
        ushort4 vh = *(const ushort4*)&Thi[d][half * 4];
        *(ushort4*)&HhiT[d * N_ROWS + i_base + half * 4] = vh;
        ushort4 vl = *(const ushort4*)&Tlo[d][half * 4];
        *(ushort4*)&HloT[d * N_ROWS + i_base + half * 4] = vl;
    }
}

// ---------------------------------------------------------------------------
// K2: single-pass attention. 256 blocks x 512 threads (8 waves).
// Block = 8 output rows x ALL 2048 j. Wave w covers j in [w*256, w*256+256)
// as 4 iterations of a 16x64 W tile (rows 8..15 zero-padded once). adj for
// the next iteration is prefetched during MFMA of the current one.
// After the j loop: one __syncthreads, cross-wave combine of the 8 waves'
// numerator/denominator partials in LDS, normalize, ELU, store out directly.
// No partial workspace, no third kernel. adj traffic = exactly 16.8 MB.
// ---------------------------------------------------------------------------
__global__ __launch_bounds__(512) void k2_attn(
    const int* __restrict__ adj, const float* __restrict__ s_buf,
    const unsigned short* __restrict__ HhiT, const unsigned short* __restrict__ HloT,
    const float* __restrict__ muB, float* __restrict__ out)
{
    __shared__ __align__(16) unsigned short Wt[8][16][72];   // 18.4 KB
    __shared__ f32x4 cN[8][4][64];                           // 32 KB
    __shared__ f32x4 cL[8][64];                              // 8 KB

    const int tid  = threadIdx.x;
    const int w    = tid >> 6;                 // 0..7
    const int lane = tid & 63;
    const int i0 = blockIdx.x * 8;             // 8-row stripe
    const float mub = muB[0];

    const int rsel = lane & 15;                // A row / C col
    const int rsub = lane >> 4;                // k-chunk / C row-group

    // ---- zero-pad W rows 8..15 once (read every iter, never rewritten)
    if (rsel >= 8) {
        #pragma unroll
        for (int z = 0; z < 18; ++z)
            Wt[w][rsel][rsub * 18 + z] = 0;
    }

    f32x4 accN[4];
    f32x4 accL;
    #pragma unroll
    for (int nb = 0; nb < 4; ++nb) { accN[nb][0]=0.f; accN[nb][1]=0.f; accN[nb][2]=0.f; accN[nb][3]=0.f; }
    accL[0]=0.f; accL[1]=0.f; accL[2]=0.f; accL[3]=0.f;

    s16x8 ones;
    #pragma unroll
    for (int e = 0; e < 8; ++e) ones[e] = (short)0x3F80;  // bf16 1.0

    const int4* adj4 = (const int4*)adj;
    const float si0 = s_buf[i0 + rsub];        // rows rsub, rsub+4
    const float si1 = s_buf[i0 + 4 + rsub];

    // ---- prefetch iteration 0
    int4 aNxt0 = adj4[(size_t)(i0 + rsub)     * (N_ROWS / 4) + ((w * 256) >> 2) + rsel];
    int4 aNxt1 = adj4[(size_t)(i0 + 4 + rsub) * (N_ROWS / 4) + ((w * 256) >> 2) + rsel];

    #pragma unroll
    for (int it = 0; it < 4; ++it) {
        const int jb = w * 256 + it * 64;
        const float4 sj4 = ((const float4*)s_buf)[(jb >> 2) + rsel];
        int4 a0v = aNxt0, a1v = aNxt1;
        if (it < 3) {                          // prefetch next j-tile
            const int jn = (jb + 64) >> 2;
            aNxt0 = adj4[(size_t)(i0 + rsub)     * (N_ROWS / 4) + jn + rsel];
            aNxt1 = adj4[(size_t)(i0 + 4 + rsub) * (N_ROWS / 4) + jn + rsel];
        }
        // ---- build rows rsub (0..3) and 4+rsub (4..7) of the W tile
        {
            ushort4 pk;
            { float z = si0 + sj4.x + mub; float e = z > 0.f ? z : ALPHA * z; pk.x = a0v.x ? f2bf(__expf(e)) : 0; }
            { float z = si0 + sj4.y + mub; float e = z > 0.f ? z : ALPHA * z; pk.y = a0v.y ? f2bf(__expf(e)) : 0; }
            { float z = si0 + sj4.z + mub; float e = z > 0.f ? z : ALPHA * z; pk.z = a0v.z ? f2bf(__expf(e)) : 0; }
            { float z = si0 + sj4.w + mub; float e = z > 0.f ? z : ALPHA * z; pk.w = a0v.w ? f2bf(__expf(e)) : 0; }
            *(ushort4*)&Wt[w][rsub][rsel * 4] = pk;
        }
        {
            ushort4 pk;
            { float z = si1 + sj4.x + mub; float e = z > 0.f ? z : ALPHA * z; pk.x = a1v.x ? f2bf(__expf(e)) : 0; }
            { float z = si1 + sj4.y + mub; float e = z > 0.f ? z : ALPHA * z; pk.y = a1v.y ? f2bf(__expf(e)) : 0; }
            { float z = si1 + sj4.z + mub; float e = z > 0.f ? z : ALPHA * z; pk.z = a1v.z ? f2bf(__expf(e)) : 0; }
            { float z = si1 + sj4.w + mub; float e = z > 0.f ? z : ALPHA * z; pk.w = a1v.w ? f2bf(__expf(e)) : 0; }
            *(ushort4*)&Wt[w][4 + rsub][rsel * 4] = pk;
        }

        // ---- A fragments (same-wave LDS dependency; compiler emits lgkmcnt)
        s16x8 af0 = *(const s16x8*)&Wt[w][rsel][rsub * 8];
        s16x8 af1 = *(const s16x8*)&Wt[w][rsel][32 + rsub * 8];

        accL = __builtin_amdgcn_mfma_f32_16x16x32_bf16(af0, ones, accL, 0, 0, 0);
        accL = __builtin_amdgcn_mfma_f32_16x16x32_bf16(af1, ones, accL, 0, 0, 0);
        #pragma unroll
        for (int nb = 0; nb < 4; ++nb) {
            const unsigned short* hr = HhiT + (size_t)(nb * 16 + rsel) * N_ROWS + jb + rsub * 8;
            s16x8 b0 = *(const s16x8*)hr;
            s16x8 b1 = *(const s16x8*)(hr + 32);
            accN[nb] = __builtin_amdgcn_mfma_f32_16x16x32_bf16(af0, b0, accN[nb], 0, 0, 0);
            accN[nb] = __builtin_amdgcn_mfma_f32_16x16x32_bf16(af1, b1, accN[nb], 0, 0, 0);
            const unsigned short* lr = HloT + (size_t)(nb * 16 + rsel) * N_ROWS + jb + rsub * 8;
            s16x8 c0 = *(const s16x8*)lr;
            s16x8 c1 = *(const s16x8*)(lr + 32);
            accN[nb] = __builtin_amdgcn_mfma_f32_16x16x32_bf16(af0, c0, accN[nb], 0, 0, 0);
            accN[nb] = __builtin_amdgcn_mfma_f32_16x16x32_bf16(af1, c1, accN[nb], 0, 0, 0);
        }
    }

    // ---- cross-wave combine over 8 waves, then finish in-place
    #pragma unroll
    for (int nb = 0; nb < 4; ++nb) cN[w][nb][lane] = accN[nb];
    cL[w][lane] = accL;
    __syncthreads();

    if (w < 4) {       // wave w owns column-block nb = w
        f32x4 n = {0.f, 0.f, 0.f, 0.f};
        f32x4 l = {0.f, 0.f, 0.f, 0.f};
        #pragma unroll
        for (int v = 0; v < 8; ++v) {
            n += cN[v][w][lane];
            l += cL[v][lane];
        }
        if (rsub < 2) {            // C rows rsub*4+r = 0..7 are the real rows
            #pragma unroll
            for (int r = 0; r < 4; ++r) {
                const int row = rsub * 4 + r;
                float val = n[r] / l[r];
                val = val > 0.f ? val : expm1f(val);
                out[(i0 + row) * D_OUT + w * 16 + rsel] = val;
            }
        }
    }
}

// ---------------------------------------------------------------------------
extern "C" void kernel_launch(void* const* d_in, const int* in_sizes, int n_in,
                              void* d_out, int out_size, void* d_ws, size_t ws_size,
                              hipStream_t stream)
{
    const float* F    = (const float*)d_in[0];
    const int*   adj  = (const int*)d_in[1];
    const float* phiW = (const float*)d_in[2];
    const float* phiB = (const float*)d_in[3];
    const float* lnG  = (const float*)d_in[4];
    const float* lnB  = (const float*)d_in[5];
    const float* muW  = (const float*)d_in[6];
    const float* muB  = (const float*)d_in[7];
    float* out = (float*)d_out;

    float* ws   = (float*)d_ws;
    float* s    = ws;                                   // 2048 f32
    unsigned short* HhiT = (unsigned short*)(ws + N_ROWS);      // 64*2048 bf16
    unsigned short* HloT = HhiT + (size_t)D_OUT * N_ROWS;

    k1_h_s<<<dim3(256), dim3(256), 0, stream>>>(F, phiW, phiB, lnG, lnB, muW,
                                                s, HhiT, HloT);
    k2_attn<<<dim3(256), dim3(512), 0, stream>>>(adj, s, HhiT, HloT, muB, out);
}